// Round 3
// baseline (296.231 us; speedup 1.0000x reference)
//
#include <hip/hip_runtime.h>
#include <hip/hip_bf16.h>

// GCN 2-layer: z = relu(A(relu(A(xW1)+b1)W2)+b2), A = D^-1/2 (Adj+I) D^-1/2
// N=50000 nodes, E=800000 edges, D=128. Output dtype: float32.

__global__ void k_init(int* degi, int* cursor, int n) {
    int i = blockIdx.x * blockDim.x + threadIdx.x;
    if (i < n) { degi[i] = 0; cursor[i] = 0; }
}

__global__ void k_hist(const int* __restrict__ col, int* degi, int E) {
    int i = blockIdx.x * blockDim.x + threadIdx.x;
    if (i < E) atomicAdd(&degi[col[i]], 1);
}

__global__ void k_dinv(const int* __restrict__ degi, float* dinv, int n) {
    int i = blockIdx.x * blockDim.x + threadIdx.x;
    if (i < n) dinv[i] = rsqrtf((float)degi[i] + 1.0f);  // +1 self loop, never 0
}

// --- exclusive scan over degi -> startv (3 kernels) ---
__global__ void k_scan_a(const int* __restrict__ degi, int* excl, int* partials, int n) {
    __shared__ int s[256];
    int t = threadIdx.x;
    int i = blockIdx.x * 256 + t;
    int v = (i < n) ? degi[i] : 0;
    s[t] = v; __syncthreads();
    for (int o = 1; o < 256; o <<= 1) {
        int x = (t >= o) ? s[t - o] : 0;
        __syncthreads();
        s[t] += x;
        __syncthreads();
    }
    if (i < n) excl[i] = s[t] - v;
    if (t == 255) partials[blockIdx.x] = s[255];
}

__global__ void k_scan_b(int* partials, int nb) {
    __shared__ int s[256];
    int t = threadIdx.x;
    int v = (t < nb) ? partials[t] : 0;
    s[t] = v; __syncthreads();
    for (int o = 1; o < 256; o <<= 1) {
        int x = (t >= o) ? s[t - o] : 0;
        __syncthreads();
        s[t] += x;
        __syncthreads();
    }
    if (t < nb) partials[t] = s[t] - v;  // exclusive
}

__global__ void k_scan_c(int* excl, const int* __restrict__ partials, int n) {
    int i = blockIdx.x * 256 + threadIdx.x;
    if (i < n) excl[i] += partials[blockIdx.x];
}

__global__ void k_fill(const int* __restrict__ row, const int* __restrict__ col,
                       const int* __restrict__ startv, int* cursor, int* srcs, int E) {
    int e = blockIdx.x * blockDim.x + threadIdx.x;
    if (e < E) {
        int c = col[e];
        int p = startv[c] + atomicAdd(&cursor[c], 1);
        srcs[p] = row[e];
    }
}

// --- C[M,128] = A[M,128] @ W[128,128], f32 vector GEMM ---
// block 256 thr, tile 64 rows x 128 cols, thread = 8 rows x 4 cols.
// LDS: only the transposed X tile (34.8 KB, under the 64 KB/workgroup limit).
// W is read from global per-k (one 512B row per wave per k, L1/L2 resident).
__global__ __launch_bounds__(256) void k_gemm(const float* __restrict__ A,
                                              const float* __restrict__ W,
                                              float* __restrict__ C, int M) {
    __shared__ float Xl[128][68];     // Xl[k][r] = A[row0+r][k]; pad 68 for banks
    const int t = threadIdx.x;
    const int row0 = blockIdx.x * 64;

    // stage X transposed: coalesced float4 reads
    for (int c = t; c < 2048; c += 256) {
        int kq = c & 31, r = c >> 5;
        float4 v = make_float4(0.f, 0.f, 0.f, 0.f);
        int gr = row0 + r;
        if (gr < M) v = ((const float4*)A)[gr * 32 + kq];
        Xl[4 * kq + 0][r] = v.x;
        Xl[4 * kq + 1][r] = v.y;
        Xl[4 * kq + 2][r] = v.z;
        Xl[4 * kq + 3][r] = v.w;
    }
    __syncthreads();

    const int cg = t & 31;   // cols 4*cg .. +4
    const int rg = t >> 5;   // rows 8*rg .. +8
    float acc[8][4];
#pragma unroll
    for (int i = 0; i < 8; i++)
#pragma unroll
        for (int j = 0; j < 4; j++) acc[i][j] = 0.f;

    const float4* Wv = (const float4*)W;
#pragma unroll 4
    for (int k = 0; k < 128; k++) {
        const float4 w  = Wv[(k << 5) + cg];              // W[k][4cg..4cg+3]
        const float4 xa = *(const float4*)(&Xl[k][rg << 3]);
        const float4 xb = *(const float4*)(&Xl[k][(rg << 3) + 4]);
        const float xs[8] = {xa.x, xa.y, xa.z, xa.w, xb.x, xb.y, xb.z, xb.w};
        const float ws4[4] = {w.x, w.y, w.z, w.w};
#pragma unroll
        for (int i = 0; i < 8; i++)
#pragma unroll
            for (int j = 0; j < 4; j++) acc[i][j] = fmaf(xs[i], ws4[j], acc[i][j]);
    }

#pragma unroll
    for (int i = 0; i < 8; i++) {
        int row = row0 + (rg << 3) + i;
        if (row < M) {
            float4 o = make_float4(acc[i][0], acc[i][1], acc[i][2], acc[i][3]);
            *(float4*)(C + row * 128 + (cg << 2)) = o;
        }
    }
}

// --- aggregation: out[i] = relu(dinv[i]*(sum_j dinv[j]*H[j] + dinv[i]*H[i]) + b) ---
// one wave (64 lanes) per node; lane holds a float2 (features 2*lane, 2*lane+1).
// Neighbor indices + dinv prefetched 64-wide, broadcast via shfl.
__global__ __launch_bounds__(256) void k_agg(const float* __restrict__ H,
                                             const int* __restrict__ srcs,
                                             const int* __restrict__ startv,
                                             const int* __restrict__ degi,
                                             const float* __restrict__ dinv,
                                             const float* __restrict__ bias,
                                             float* __restrict__ out, int n) {
    int wave = threadIdx.x >> 6, lane = threadIdx.x & 63;
    int node = blockIdx.x * 4 + wave;
    if (node >= n) return;
    int s0 = startv[node];
    int d = degi[node];
    float di = dinv[node];
    const float2* Hv = (const float2*)H;

    float2 hv = Hv[(size_t)node * 64 + lane];   // self term
    float ax = di * hv.x, ay = di * hv.y;

    for (int k = 0; k < d; k += 64) {
        int take = d - k; if (take > 64) take = 64;
        int idx = (lane < take) ? srcs[s0 + k + lane] : 0;
        float djl = (lane < take) ? dinv[idx] : 0.f;
        for (int u = 0; u < take; u++) {
            int j = __shfl(idx, u);
            float dj = __shfl(djl, u);
            float2 v = Hv[(size_t)j * 64 + lane];
            ax = fmaf(dj, v.x, ax);
            ay = fmaf(dj, v.y, ay);
        }
    }
    float bx = bias[2 * lane], by = bias[2 * lane + 1];
    float ox = fmaxf(fmaf(di, ax, bx), 0.f);
    float oy = fmaxf(fmaf(di, ay, by), 0.f);
    ((float2*)out)[(size_t)node * 64 + lane] = make_float2(ox, oy);
}

extern "C" void kernel_launch(void* const* d_in, const int* in_sizes, int n_in,
                              void* d_out, int out_size, void* d_ws, size_t ws_size,
                              hipStream_t stream) {
    const float* x  = (const float*)d_in[0];
    const int*   ei = (const int*)d_in[1];
    const float* W1 = (const float*)d_in[2];
    const float* b1 = (const float*)d_in[3];
    const float* W2 = (const float*)d_in[4];
    const float* b2 = (const float*)d_in[5];
    const int N = in_sizes[0] / 128;
    const int E = in_sizes[1] / 2;

    char* w = (char*)d_ws;
    auto alloc = [&](size_t bytes) -> void* {
        void* p = (void*)w;
        w += (bytes + 255) & ~(size_t)255;
        return p;
    };
    int*   degi     = (int*)alloc((size_t)N * 4);
    int*   cursor   = (int*)alloc((size_t)N * 4);
    float* dinv     = (float*)alloc((size_t)N * 4);
    int*   startv   = (int*)alloc((size_t)N * 4);
    int*   partials = (int*)alloc(1024);
    int*   srcs     = (int*)alloc((size_t)E * 4);
    float* H        = (float*)alloc((size_t)N * 128 * 4);
    float* Z        = (float*)alloc((size_t)N * 128 * 4);

    const int* rowp = ei;
    const int* colp = ei + E;
    const int nbN = (N + 255) / 256;
    const int nbE = (E + 255) / 256;

    k_init<<<nbN, 256, 0, stream>>>(degi, cursor, N);
    k_hist<<<nbE, 256, 0, stream>>>(colp, degi, E);
    k_dinv<<<nbN, 256, 0, stream>>>(degi, dinv, N);
    k_scan_a<<<nbN, 256, 0, stream>>>(degi, startv, partials, N);
    k_scan_b<<<1, 256, 0, stream>>>(partials, nbN);
    k_scan_c<<<nbN, 256, 0, stream>>>(startv, partials, N);
    k_fill<<<nbE, 256, 0, stream>>>(rowp, colp, startv, cursor, srcs, E);

    k_gemm<<<(N + 63) / 64, 256, 0, stream>>>(x, W1, H, N);
    k_agg<<<(N + 3) / 4, 256, 0, stream>>>(H, srcs, startv, degi, dinv, b1, Z, N);
    k_gemm<<<(N + 63) / 64, 256, 0, stream>>>(Z, W2, H, N);
    k_agg<<<(N + 3) / 4, 256, 0, stream>>>(H, srcs, startv, degi, dinv, b2,
                                           (float*)d_out, N);
}

// Round 4
// 228.124 us; speedup vs baseline: 1.2986x; 1.2986x over previous
//
#include <hip/hip_runtime.h>
#include <hip/hip_bf16.h>
#include <hip/hip_fp16.h>

// GCN 2-layer: z = relu(A(relu(A(xW1)+b1)W2)+b2), A = D^-1/2 (Adj+I) D^-1/2
// N=50000, E=800000, D=128. Output: float32.
// Post-GEMM features stored fp16 to halve the scatter-gather volume.

__global__ void k_init(int* degi, int* cursor, int n) {
    int i = blockIdx.x * blockDim.x + threadIdx.x;
    if (i < n) { degi[i] = 0; cursor[i] = 0; }
}

__global__ void k_hist(const int* __restrict__ col, int* degi, int E) {
    int i = blockIdx.x * blockDim.x + threadIdx.x;
    if (i < E) atomicAdd(&degi[col[i]], 1);
}

// local exclusive scan + per-block sums; also computes dinv = rsqrt(deg+1)
__global__ void k_scan_a(const int* __restrict__ degi, int* excl, int* partials,
                         float* dinv, int n) {
    __shared__ int s[256];
    int t = threadIdx.x;
    int i = blockIdx.x * 256 + t;
    int v = (i < n) ? degi[i] : 0;
    s[t] = v; __syncthreads();
    for (int o = 1; o < 256; o <<= 1) {
        int x = (t >= o) ? s[t - o] : 0;
        __syncthreads();
        s[t] += x;
        __syncthreads();
    }
    if (i < n) {
        excl[i] = s[t] - v;
        dinv[i] = rsqrtf((float)v + 1.0f);   // +1 self loop, never 0
    }
    if (t == 255) partials[blockIdx.x] = s[255];
}

__global__ void k_scan_b(int* partials, int nb) {
    __shared__ int s[256];
    int t = threadIdx.x;
    int v = (t < nb) ? partials[t] : 0;
    s[t] = v; __syncthreads();
    for (int o = 1; o < 256; o <<= 1) {
        int x = (t >= o) ? s[t - o] : 0;
        __syncthreads();
        s[t] += x;
        __syncthreads();
    }
    if (t < nb) partials[t] = s[t] - v;  // exclusive over blocks
}

// startv[c] computed on the fly: excl[c] + partials[c>>8]
__global__ void k_fill(const int* __restrict__ row, const int* __restrict__ col,
                       const int* __restrict__ excl, const int* __restrict__ partials,
                       int* cursor, int* srcs, int E) {
    int e = blockIdx.x * blockDim.x + threadIdx.x;
    if (e < E) {
        int c = col[e];
        int p = excl[c] + partials[c >> 8] + atomicAdd(&cursor[c], 1);
        srcs[p] = row[e];
    }
}

// --- C[M,128] = A[M,128] @ W[128,128], f32 vector GEMM, fp16 output ---
// block 256 thr, tile 64 rows x 128 cols, thread = 8 rows x 4 cols.
__global__ __launch_bounds__(256) void k_gemm(const float* __restrict__ A,
                                              const float* __restrict__ W,
                                              __half* __restrict__ C, int M) {
    __shared__ float Xl[128][68];     // Xl[k][r] = A[row0+r][k]; pad 68 for banks
    const int t = threadIdx.x;
    const int row0 = blockIdx.x * 64;

    for (int c = t; c < 2048; c += 256) {
        int kq = c & 31, r = c >> 5;
        float4 v = make_float4(0.f, 0.f, 0.f, 0.f);
        int gr = row0 + r;
        if (gr < M) v = ((const float4*)A)[gr * 32 + kq];
        Xl[4 * kq + 0][r] = v.x;
        Xl[4 * kq + 1][r] = v.y;
        Xl[4 * kq + 2][r] = v.z;
        Xl[4 * kq + 3][r] = v.w;
    }
    __syncthreads();

    const int cg = t & 31;   // cols 4*cg .. +4
    const int rg = t >> 5;   // rows 8*rg .. +8
    float acc[8][4];
#pragma unroll
    for (int i = 0; i < 8; i++)
#pragma unroll
        for (int j = 0; j < 4; j++) acc[i][j] = 0.f;

    const float4* Wv = (const float4*)W;
#pragma unroll 4
    for (int k = 0; k < 128; k++) {
        const float4 w  = Wv[(k << 5) + cg];              // W[k][4cg..4cg+3]
        const float4 xa = *(const float4*)(&Xl[k][rg << 3]);
        const float4 xb = *(const float4*)(&Xl[k][(rg << 3) + 4]);
        const float xs[8] = {xa.x, xa.y, xa.z, xa.w, xb.x, xb.y, xb.z, xb.w};
        const float ws4[4] = {w.x, w.y, w.z, w.w};
#pragma unroll
        for (int i = 0; i < 8; i++)
#pragma unroll
            for (int j = 0; j < 4; j++) acc[i][j] = fmaf(xs[i], ws4[j], acc[i][j]);
    }

#pragma unroll
    for (int i = 0; i < 8; i++) {
        int row = row0 + (rg << 3) + i;
        if (row < M) {
            __half2 p0 = __floats2half2_rn(acc[i][0], acc[i][1]);
            __half2 p1 = __floats2half2_rn(acc[i][2], acc[i][3]);
            uint2 pk;
            pk.x = *reinterpret_cast<unsigned*>(&p0);
            pk.y = *reinterpret_cast<unsigned*>(&p1);
            ((uint2*)C)[row * 32 + cg] = pk;   // 8B store, cols 4cg..4cg+3
        }
    }
}

// --- aggregation: out = relu(di*(sum_j dj*H[j] + di*H[i]) + b), H fp16 ---
// one wave per node; lane holds features (2*lane, 2*lane+1) as __half2.
__global__ __launch_bounds__(256) void k_agg(const __half* __restrict__ H,
                                             const int* __restrict__ srcs,
                                             const int* __restrict__ excl,
                                             const int* __restrict__ partials,
                                             const int* __restrict__ degi,
                                             const float* __restrict__ dinv,
                                             const float* __restrict__ bias,
                                             float* __restrict__ outF,
                                             __half* __restrict__ outH, int n) {
    int wave = threadIdx.x >> 6, lane = threadIdx.x & 63;
    int node = blockIdx.x * 4 + wave;
    if (node >= n) return;
    int s0 = excl[node] + partials[node >> 8];
    int d = degi[node];
    float di = dinv[node];
    const __half2* Hv = (const __half2*)H;

    float2 hv = __half22float2(Hv[(size_t)node * 64 + lane]);   // self term
    float ax = di * hv.x, ay = di * hv.y;

    for (int k = 0; k < d; k += 64) {
        int take = d - k; if (take > 64) take = 64;
        int idx = (lane < take) ? srcs[s0 + k + lane] : 0;
        float djl = (lane < take) ? dinv[idx] : 0.f;
        int u = 0;
        for (; u + 4 <= take; u += 4) {      // 4-deep MLP
            int j0 = __shfl(idx, u),     j1 = __shfl(idx, u + 1);
            int j2 = __shfl(idx, u + 2), j3 = __shfl(idx, u + 3);
            float d0 = __shfl(djl, u),     d1 = __shfl(djl, u + 1);
            float d2 = __shfl(djl, u + 2), d3 = __shfl(djl, u + 3);
            float2 v0 = __half22float2(Hv[(size_t)j0 * 64 + lane]);
            float2 v1 = __half22float2(Hv[(size_t)j1 * 64 + lane]);
            float2 v2 = __half22float2(Hv[(size_t)j2 * 64 + lane]);
            float2 v3 = __half22float2(Hv[(size_t)j3 * 64 + lane]);
            ax = fmaf(d0, v0.x, ax); ay = fmaf(d0, v0.y, ay);
            ax = fmaf(d1, v1.x, ax); ay = fmaf(d1, v1.y, ay);
            ax = fmaf(d2, v2.x, ax); ay = fmaf(d2, v2.y, ay);
            ax = fmaf(d3, v3.x, ax); ay = fmaf(d3, v3.y, ay);
        }
        for (; u < take; u++) {
            int j = __shfl(idx, u);
            float dj = __shfl(djl, u);
            float2 v = __half22float2(Hv[(size_t)j * 64 + lane]);
            ax = fmaf(dj, v.x, ax); ay = fmaf(dj, v.y, ay);
        }
    }
    float2 b2 = ((const float2*)bias)[lane];
    float ox = fmaxf(fmaf(di, ax, b2.x), 0.f);
    float oy = fmaxf(fmaf(di, ay, b2.y), 0.f);
    if (outF) {
        ((float2*)outF)[(size_t)node * 64 + lane] = make_float2(ox, oy);
    } else {
        __half2 p = __floats2half2_rn(ox, oy);
        ((__half2*)outH)[(size_t)node * 64 + lane] = p;
    }
}

extern "C" void kernel_launch(void* const* d_in, const int* in_sizes, int n_in,
                              void* d_out, int out_size, void* d_ws, size_t ws_size,
                              hipStream_t stream) {
    const float* x  = (const float*)d_in[0];
    const int*   ei = (const int*)d_in[1];
    const float* W1 = (const float*)d_in[2];
    const float* b1 = (const float*)d_in[3];
    const float* W2 = (const float*)d_in[4];
    const float* b2 = (const float*)d_in[5];
    const int N = in_sizes[0] / 128;
    const int E = in_sizes[1] / 2;

    char* w = (char*)d_ws;
    auto alloc = [&](size_t bytes) -> void* {
        void* p = (void*)w;
        w += (bytes + 255) & ~(size_t)255;
        return p;
    };
    int*    degi     = (int*)alloc((size_t)N * 4);
    int*    cursor   = (int*)alloc((size_t)N * 4);
    float*  dinv     = (float*)alloc((size_t)N * 4);
    int*    excl     = (int*)alloc((size_t)N * 4);
    int*    partials = (int*)alloc(1024);
    int*    srcs     = (int*)alloc((size_t)E * 4);
    __half* H        = (__half*)alloc((size_t)N * 128 * 2);
    float*  Z        = (float*)alloc((size_t)N * 128 * 4);

    const int* rowp = ei;
    const int* colp = ei + E;
    const int nbN = (N + 255) / 256;
    const int nbE = (E + 255) / 256;

    k_init<<<nbN, 256, 0, stream>>>(degi, cursor, N);
    k_hist<<<nbE, 256, 0, stream>>>(colp, degi, E);
    k_scan_a<<<nbN, 256, 0, stream>>>(degi, excl, partials, dinv, N);
    k_scan_b<<<1, 256, 0, stream>>>(partials, nbN);
    k_fill<<<nbE, 256, 0, stream>>>(rowp, colp, excl, partials, cursor, srcs, E);

    k_gemm<<<(N + 63) / 64, 256, 0, stream>>>(x, W1, H, N);
    k_agg<<<(N + 3) / 4, 256, 0, stream>>>(H, srcs, excl, partials, degi, dinv, b1,
                                           Z, nullptr, N);
    k_gemm<<<(N + 63) / 64, 256, 0, stream>>>(Z, W2, H, N);
    k_agg<<<(N + 3) / 4, 256, 0, stream>>>(H, srcs, excl, partials, degi, dinv, b2,
                                           (float*)d_out, nullptr, N);
}